// Round 1
// baseline (5995.317 us; speedup 1.0000x reference)
//
#include <hip/hip_runtime.h>
#include <cstdint>
#include <cstddef>

// ---------------------------------------------------------------------------
// MultiScaleSTN — fp32 baseline (round 0: correctness-first)
//
// Algebraic fusion: x0 = conv0(corr) where corr = tgt^T·src  ==>
//   E_l[b,o,c] = sum_t w0[o, l*1024+t] * tgt_l[b,c,t]       (per scale)
//   x0[b,o,s]  = BN+leaky( sum_l sum_c E_l[b,o,c]*src_l[b,c,s] )
// This avoids materializing the 67MB corr tensor entirely.
// ---------------------------------------------------------------------------

constexpr int BATCH = 8;
constexpr int CH    = 256;   // feature channels
constexpr int SS    = 32;    // spatial
constexpr int HW    = 1024;  // SS*SS
constexpr float BN_EPS = 1e-5f;
constexpr float SLOPE  = 0.1f;

// workspace layout in floats
constexpr size_t OFF_E    = 0;         // [B,2,1024,256]  = 4,194,304
constexpr size_t OFF_X0   = 4194304;   // [B,1024,1024]   = 8,388,608
constexpr size_t OFF_WARP = 12582912;  // 2 x [B,256,1024]= 4,194,304
constexpr size_t OFF_X1   = 0;         // alias E  (E dead after x0 kernel)
constexpr size_t OFF_X2   = 12582912;  // alias WARP (warp dead after x0 kernel)
constexpr size_t OFF_FLOW = 16777216;  // [B,1024,2]      = 16,384
// total: 16,793,600 floats = 67.2 MB

// ---------------------------------------------------------------------------
// E kernel: E[b,o,c] = sum_t w0[o, lofs+t] * tgt[b,c,t]
// GEMM tile 64(o) x 64(c), K=1024 (t), BK=16
// ---------------------------------------------------------------------------
__global__ __launch_bounds__(256) void e_kernel(
    const float* __restrict__ w0s,   // [1024, 2048] scale slice
    const float* __restrict__ tgt,   // [B, 256, 1024]
    float* __restrict__ Eout,        // E + l*262144 ; batch stride 524288
    int lofs)                        // l*1024
{
    __shared__ __align__(16) float ash[16][68];
    __shared__ __align__(16) float bsh[16][68];
    const int c0 = blockIdx.x * 64;
    const int o0 = blockIdx.y * 64;
    const int b  = blockIdx.z;
    const int tid = threadIdx.x;
    const int tx = tid & 15, ty = tid >> 4;

    float acc[4][4] = {};
    const float* tb = tgt + (size_t)b * (CH * HW);

    for (int k0 = 0; k0 < HW; k0 += 16) {
        {   // a: w0 rows o (contiguous in t) -> transpose-store  ash[k][oo]
            const int oo = tid >> 2;
            const int kk = (tid & 3) * 4;
            const float4 a4 = *(const float4*)(w0s + (size_t)(o0 + oo) * 2048 + lofs + k0 + kk);
            ash[kk + 0][oo] = a4.x; ash[kk + 1][oo] = a4.y;
            ash[kk + 2][oo] = a4.z; ash[kk + 3][oo] = a4.w;
        }
        {   // b[k][cc] = tgt[b, c0+cc, k0+k]  (contiguous in t) -> transpose-store
            const int cc = tid >> 2;
            const int kk = (tid & 3) * 4;
            const float4 b4 = *(const float4*)(tb + (size_t)(c0 + cc) * HW + k0 + kk);
            bsh[kk + 0][cc] = b4.x; bsh[kk + 1][cc] = b4.y;
            bsh[kk + 2][cc] = b4.z; bsh[kk + 3][cc] = b4.w;
        }
        __syncthreads();
        #pragma unroll
        for (int k = 0; k < 16; ++k) {
            const float4 av = *(const float4*)&ash[k][ty * 4];
            const float4 bv = *(const float4*)&bsh[k][tx * 4];
            const float ar[4] = {av.x, av.y, av.z, av.w};
            const float br[4] = {bv.x, bv.y, bv.z, bv.w};
            #pragma unroll
            for (int r = 0; r < 4; ++r)
                #pragma unroll
                for (int c = 0; c < 4; ++c)
                    acc[r][c] += ar[r] * br[c];
        }
        __syncthreads();
    }
    #pragma unroll
    for (int r = 0; r < 4; ++r) {
        float4 v = make_float4(acc[r][0], acc[r][1], acc[r][2], acc[r][3]);
        *(float4*)(Eout + (size_t)b * 524288 + (size_t)(o0 + ty * 4 + r) * 256 + c0 + tx * 4) = v;
    }
}

// ---------------------------------------------------------------------------
// x0 kernel: x0[b,o,s] = BN+leaky( sum_{l,c} E[b,l,o,c] * src_l[b,c,s] )
// GEMM tile 64(o) x 64(s), K = 2*256 = 512, BK=16
// ---------------------------------------------------------------------------
__global__ __launch_bounds__(256) void x0_kernel(
    const float* __restrict__ E,     // [B,2,1024,256]
    const float* __restrict__ s2,    // [B,256,1024]
    const float* __restrict__ s3,    // [B,256,1024]
    const float* __restrict__ bng, const float* __restrict__ bnb,
    const float* __restrict__ bnm, const float* __restrict__ bnv,
    float* __restrict__ out)         // [B,1024,1024]
{
    __shared__ __align__(16) float ash[16][68];
    __shared__ __align__(16) float bsh[16][68];
    const int s0 = blockIdx.x * 64;
    const int o0 = blockIdx.y * 64;
    const int bz = blockIdx.z;
    const int tid = threadIdx.x;
    const int tx = tid & 15, ty = tid >> 4;

    float acc[4][4] = {};
    const float* Eb = E + (size_t)bz * 524288;

    for (int k0 = 0; k0 < 512; k0 += 16) {
        const int l  = k0 >> 8;
        const int c0 = k0 & 255;
        const float* sl = (l == 0 ? s2 : s3) + (size_t)bz * (CH * HW);
        {   // a: E rows o (contiguous in c) -> transpose-store
            const int oo = tid >> 2;
            const int kk = (tid & 3) * 4;
            const float4 a4 = *(const float4*)(Eb + (size_t)l * 262144 + (size_t)(o0 + oo) * 256 + c0 + kk);
            ash[kk + 0][oo] = a4.x; ash[kk + 1][oo] = a4.y;
            ash[kk + 2][oo] = a4.z; ash[kk + 3][oo] = a4.w;
        }
        {   // b[k][ss2] = src_l[b, c0+k, s0+ss2]  (direct, coalesced)
            const int kk = tid >> 4;
            const int ss2 = (tid & 15) * 4;
            *(float4*)&bsh[kk][ss2] = *(const float4*)(sl + (size_t)(c0 + kk) * HW + s0 + ss2);
        }
        __syncthreads();
        #pragma unroll
        for (int k = 0; k < 16; ++k) {
            const float4 av = *(const float4*)&ash[k][ty * 4];
            const float4 bv = *(const float4*)&bsh[k][tx * 4];
            const float ar[4] = {av.x, av.y, av.z, av.w};
            const float br[4] = {bv.x, bv.y, bv.z, bv.w};
            #pragma unroll
            for (int r = 0; r < 4; ++r)
                #pragma unroll
                for (int c = 0; c < 4; ++c)
                    acc[r][c] += ar[r] * br[c];
        }
        __syncthreads();
    }
    #pragma unroll
    for (int r = 0; r < 4; ++r) {
        const int o = o0 + ty * 4 + r;
        const float sc = bng[o] / sqrtf(bnv[o] + BN_EPS);
        const float sh = bnb[o] - bnm[o] * sc;
        float v[4];
        #pragma unroll
        for (int c = 0; c < 4; ++c) {
            float t = acc[r][c] * sc + sh;
            v[c] = t >= 0.f ? t : SLOPE * t;
        }
        *(float4*)(out + (size_t)bz * (1024 * (size_t)HW) + (size_t)o * HW + s0 + tx * 4) =
            make_float4(v[0], v[1], v[2], v[3]);
    }
}

// ---------------------------------------------------------------------------
// 3x3 conv + BN + leaky (implicit GEMM)
// block: 256 thr; tile = 32 o  x  (4 y-rows x 32 x); BK=16 input channels
// ---------------------------------------------------------------------------
template<int CIN, int COUT>
__global__ __launch_bounds__(256) void conv3x3_bn_leaky(
    const float* __restrict__ in,    // [B, CIN, 32, 32]
    const float* __restrict__ w,     // [COUT, CIN, 3, 3] scale slice
    const float* __restrict__ bng, const float* __restrict__ bnb,
    const float* __restrict__ bnm, const float* __restrict__ bnv,
    float* __restrict__ out)         // [B, COUT, 32, 32]
{
    constexpr int BK = 16;
    __shared__ __align__(16) float insh[BK][6][34];
    __shared__ __align__(16) float wsh[BK * 9][36];

    const int y0 = blockIdx.x * 4;
    const int o0 = blockIdx.y * 32;
    const int b  = blockIdx.z;
    const int tid = threadIdx.x;
    const int x = tid & 31;
    const int o_sub = tid >> 5;   // 0..7

    float acc[4][4] = {};         // [j: o][r: y]
    const float* inb = in + (size_t)b * CIN * HW;

    for (int k0 = 0; k0 < CIN; k0 += BK) {
        // stage input tile: rows y0-1 .. y0+4, x -1..32 (zero padded)
        for (int idx = tid; idx < BK * 6 * 34; idx += 256) {
            const int k   = idx / (6 * 34);
            const int rem = idx % (6 * 34);
            const int yy  = rem / 34;
            const int xx  = rem % 34;
            const int gy = y0 + yy - 1;
            const int gx = xx - 1;
            float v = 0.f;
            if (gy >= 0 && gy < SS && gx >= 0 && gx < SS)
                v = inb[(size_t)(k0 + k) * HW + gy * SS + gx];
            insh[k][yy][xx] = v;
        }
        // stage weights: per o-row 144 contiguous floats (16 i x 9 taps)
        {
            const int o = tid >> 3;
            const int rbase = (tid & 7) * 18;
            const float* g = w + (size_t)(o0 + o) * (CIN * 9) + (size_t)k0 * 9 + rbase;
            #pragma unroll
            for (int j = 0; j < 18; ++j) {
                wsh[rbase + j][o] = g[j];
            }
        }
        __syncthreads();
        #pragma unroll
        for (int k = 0; k < BK; ++k) {
            float iv[6][3];
            #pragma unroll
            for (int yy = 0; yy < 6; ++yy)
                #pragma unroll
                for (int d = 0; d < 3; ++d)
                    iv[yy][d] = insh[k][yy][x + d];
            #pragma unroll
            for (int dy = 0; dy < 3; ++dy)
                #pragma unroll
                for (int dx = 0; dx < 3; ++dx) {
                    const float4 wv = *(const float4*)&wsh[k * 9 + dy * 3 + dx][o_sub * 4];
                    #pragma unroll
                    for (int r = 0; r < 4; ++r) {
                        const float ivv = iv[r + dy][dx];
                        acc[0][r] += wv.x * ivv;
                        acc[1][r] += wv.y * ivv;
                        acc[2][r] += wv.z * ivv;
                        acc[3][r] += wv.w * ivv;
                    }
                }
        }
        __syncthreads();
    }
    #pragma unroll
    for (int j = 0; j < 4; ++j) {
        const int o = o0 + o_sub * 4 + j;
        const float sc = bng[o] / sqrtf(bnv[o] + BN_EPS);
        const float sh = bnb[o] - bnm[o] * sc;
        #pragma unroll
        for (int r = 0; r < 4; ++r) {
            float t = acc[j][r] * sc + sh;
            t = t >= 0.f ? t : SLOPE * t;
            out[(size_t)b * COUT * HW + (size_t)o * HW + (y0 + r) * SS + x] = t;
        }
    }
}

// ---------------------------------------------------------------------------
// conv3 (1x1, 256->2) + bias + flow update
// ---------------------------------------------------------------------------
__global__ __launch_bounds__(256) void conv3_flow_kernel(
    const float* __restrict__ x2,   // [B,256,1024]
    const float* __restrict__ w3s,  // [2,256]
    const float* __restrict__ b3s,  // [2]
    float* __restrict__ flow,       // [B,1024,2]
    int add_ident)
{
    const int idx = blockIdx.x * 256 + threadIdx.x;   // 8192
    const int b = idx >> 10, s = idx & 1023;
    const float* xb = x2 + (size_t)b * (CH * HW) + s;
    float a0 = 0.f, a1 = 0.f;
    #pragma unroll 4
    for (int i = 0; i < 256; ++i) {
        const float v = xb[(size_t)i * HW];
        a0 += w3s[i] * v;
        a1 += w3s[256 + i] * v;
    }
    a0 += b3s[0]; a1 += b3s[1];
    float* f = flow + (size_t)idx * 2;
    if (add_ident) {
        const int yy = s >> 5, xx = s & 31;
        f[0] = a0 + (-1.f + xx * (2.f / 31.f));
        f[1] = a1 + (-1.f + yy * (2.f / 31.f));
    } else {
        f[0] += a0;
        f[1] += a1;
    }
}

// ---------------------------------------------------------------------------
// grid_sample: bilinear, align_corners=True, zero padding
// ---------------------------------------------------------------------------
__global__ __launch_bounds__(256) void grid_sample_kernel(
    const float* __restrict__ img,   // [B,256,32,32]
    const float* __restrict__ flow,  // [B,32,32,2]
    float* __restrict__ out)         // [B,256,32,32]
{
    const int idx = blockIdx.x * 256 + threadIdx.x;  // B*C*HW = 2,097,152
    const int s = idx & 1023;
    const int b = idx >> 18;
    const float fx = flow[(size_t)b * 2048 + s * 2 + 0];
    const float fy = flow[(size_t)b * 2048 + s * 2 + 1];
    const float px = (fx + 1.f) * 15.5f;
    const float py = (fy + 1.f) * 15.5f;
    const float x0f = floorf(px), y0f = floorf(py);
    const int x0 = (int)x0f, y0 = (int)y0f;
    const float wx1 = px - x0f, wx0 = 1.f - wx1;
    const float wy1 = py - y0f, wy0 = 1.f - wy1;
    const float* ib = img + ((size_t)(idx >> 10)) * (size_t)HW;  // (b*256+c)*1024
    float v = 0.f;
    {
        const int xi = x0, yi = y0;
        if (xi >= 0 && xi < SS && yi >= 0 && yi < SS) v += ib[yi * SS + xi] * (wx0 * wy0);
    }
    {
        const int xi = x0 + 1, yi = y0;
        if (xi >= 0 && xi < SS && yi >= 0 && yi < SS) v += ib[yi * SS + xi] * (wx1 * wy0);
    }
    {
        const int xi = x0, yi = y0 + 1;
        if (xi >= 0 && xi < SS && yi >= 0 && yi < SS) v += ib[yi * SS + xi] * (wx0 * wy1);
    }
    {
        const int xi = x0 + 1, yi = y0 + 1;
        if (xi >= 0 && xi < SS && yi >= 0 && yi < SS) v += ib[yi * SS + xi] * (wx1 * wy1);
    }
    out[idx] = v;
}

__global__ __launch_bounds__(256) void copy_flow_kernel(
    const float* __restrict__ flow, float* __restrict__ out, int n)
{
    const int i = blockIdx.x * 256 + threadIdx.x;
    if (i < n) out[i] = flow[i];
}

// ---------------------------------------------------------------------------
extern "C" void kernel_launch(void* const* d_in, const int* in_sizes, int n_in,
                              void* d_out, int out_size, void* d_ws, size_t ws_size,
                              hipStream_t stream) {
    (void)in_sizes; (void)n_in; (void)ws_size;
    const float* src2 = (const float*)d_in[0];
    const float* src3 = (const float*)d_in[1];
    const float* tgt2 = (const float*)d_in[2];
    const float* tgt3 = (const float*)d_in[3];
    const float* w0   = (const float*)d_in[4];
    const float* w1   = (const float*)d_in[5];
    const float* w2   = (const float*)d_in[6];
    const float* w3   = (const float*)d_in[7];
    const float* b3   = (const float*)d_in[8];
    const float* bn0g = (const float*)d_in[9];
    const float* bn0b = (const float*)d_in[10];
    const float* bn0m = (const float*)d_in[11];
    const float* bn0v = (const float*)d_in[12];
    const float* bn1g = (const float*)d_in[13];
    const float* bn1b = (const float*)d_in[14];
    const float* bn1m = (const float*)d_in[15];
    const float* bn1v = (const float*)d_in[16];
    const float* bn2g = (const float*)d_in[17];
    const float* bn2b = (const float*)d_in[18];
    const float* bn2m = (const float*)d_in[19];
    const float* bn2v = (const float*)d_in[20];

    float* ws    = (float*)d_ws;
    float* E     = ws + OFF_E;
    float* x0    = ws + OFF_X0;
    float* warp2 = ws + OFF_WARP;
    float* warp3 = ws + OFF_WARP + 2097152;
    float* x1    = ws + OFF_X1;
    float* x2    = ws + OFF_X2;
    float* flow  = ws + OFF_FLOW;

    for (int sc = 0; sc < 3; ++sc) {
        const float* s2 = src2;
        const float* s3 = src3;
        if (sc > 0) {
            grid_sample_kernel<<<8192, 256, 0, stream>>>(src2, flow, warp2);
            grid_sample_kernel<<<8192, 256, 0, stream>>>(src3, flow, warp3);
            s2 = warp2; s3 = warp3;
        }
        const float* w0s = w0 + (size_t)sc * 2097152;
        e_kernel<<<dim3(4, 16, 8), 256, 0, stream>>>(w0s, tgt2, E, 0);
        e_kernel<<<dim3(4, 16, 8), 256, 0, stream>>>(w0s, tgt3, E + 262144, 1024);
        x0_kernel<<<dim3(16, 16, 8), 256, 0, stream>>>(E, s2, s3,
            bn0g + sc * 1024, bn0b + sc * 1024, bn0m + sc * 1024, bn0v + sc * 1024, x0);
        conv3x3_bn_leaky<1024, 512><<<dim3(8, 16, 8), 256, 0, stream>>>(
            x0, w1 + (size_t)sc * 4718592,
            bn1g + sc * 512, bn1b + sc * 512, bn1m + sc * 512, bn1v + sc * 512, x1);
        conv3x3_bn_leaky<512, 256><<<dim3(8, 8, 8), 256, 0, stream>>>(
            x1, w2 + (size_t)sc * 1179648,
            bn2g + sc * 256, bn2b + sc * 256, bn2m + sc * 256, bn2v + sc * 256, x2);
        conv3_flow_kernel<<<32, 256, 0, stream>>>(x2, w3 + sc * 512, b3 + sc * 2,
                                                  flow, sc == 0 ? 1 : 0);
    }
    copy_flow_kernel<<<(out_size + 255) / 256, 256, 0, stream>>>(flow, (float*)d_out, out_size);
}

// Round 4
// 906.404 us; speedup vs baseline: 6.6144x; 6.6144x over previous
//
#include <hip/hip_runtime.h>
#include <cstdint>
#include <cstddef>

// ---------------------------------------------------------------------------
// MultiScaleSTN — bf16 MFMA pipeline (round 1; rounds 2-3 were infra failures:
// GPUAcquisitionTimeout, kernel never ran)
//   E_l[b,o,c] = sum_t w0[o, l*1024+t] * tgt_l[b,c,t]        (GEMM, MFMA)
//   x0T[b,s,o] = BN+leaky( sum_{l,c} srcT_l[b,s,c]*E[b,l,o,c] )  (GEMM, MFMA)
//   conv1/conv2: implicit GEMM over taps, spatial-major activations
//   conv3 + flow update + grid_sample: fp32 elementwise
// ---------------------------------------------------------------------------

typedef unsigned short u16;
using bf16x8 = __attribute__((ext_vector_type(8))) short;
using f32x4  = __attribute__((ext_vector_type(4))) float;

constexpr float BN_EPS = 1e-5f;
constexpr float SLOPE  = 0.1f;

__device__ __forceinline__ u16 f2bf(float f) {
    union { float f; uint32_t u; } c; c.f = f;
    uint32_t u = c.u;
    return (u16)((u + 0x7fffu + ((u >> 16) & 1u)) >> 16);
}
__device__ __forceinline__ float bf2f(u16 h) {
    union { uint32_t u; float f; } c; c.u = ((uint32_t)h) << 16;
    return c.f;
}

#define MFMA16(a, b, c) __builtin_amdgcn_mfma_f32_16x16x32_bf16(a, b, c, 0, 0, 0)

// workspace offsets in u16 units
constexpr size_t OFF_TGT2B  = 0;          // [8][256][1024]
constexpr size_t OFF_TGT3B  = 2097152;
constexpr size_t OFF_SRCT2  = 4194304;    // [8][1024][256]
constexpr size_t OFF_SRCT3  = 6291456;
constexpr size_t OFF_WARPT2 = 8388608;    // [8][1024][256]  (aliased by x2T)
constexpr size_t OFF_WARPT3 = 10485760;
constexpr size_t OFF_W0B    = 12582912;   // [1024][2048]
constexpr size_t OFF_WPK1   = 14680064;   // [512][9][1024]
constexpr size_t OFF_WPK2   = 19398656;   // [256][9][512]
constexpr size_t OFF_E      = 20578304;   // [8*2][1024][256] (aliased by x1T)
constexpr size_t OFF_X0T    = 24772608;   // [8][1024][1024]
constexpr size_t OFF_FLOW   = 33161216;   // fp32 [8][1024][2]
// end = 33,193,984 u16 = 66.4 MB

// ---------------------------------------------------------------------------
// fp32 -> bf16, layout preserved (n multiple of 4)
__global__ __launch_bounds__(256) void cvt_kernel(
    const float* __restrict__ in, u16* __restrict__ out, int n)
{
    int i = (blockIdx.x * 256 + threadIdx.x) * 4;
    if (i + 3 < n) {
        float4 v = *(const float4*)(in + i);
        ushort4 o;
        o.x = f2bf(v.x); o.y = f2bf(v.y); o.z = f2bf(v.z); o.w = f2bf(v.w);
        *(ushort4*)(out + i) = o;
    }
}

// fp32 [8][256][1024] -> bf16 [8][1024][256] (transpose)
__global__ __launch_bounds__(256) void transpose_cvt(
    const float* __restrict__ in, u16* __restrict__ out)
{
    __shared__ float tile[32][33];
    const int s0 = blockIdx.x * 32;
    const int c0 = blockIdx.y * 32;
    const int b  = blockIdx.z;
    const int tid = threadIdx.x;
    const int tx = tid & 31, ty = tid >> 5;
    const float* ib = in + ((size_t)b * 256 + c0) * 1024 + s0;
    #pragma unroll
    for (int r = 0; r < 4; ++r)
        tile[ty + r * 8][tx] = ib[(size_t)(ty + r * 8) * 1024 + tx];
    __syncthreads();
    u16* ob = out + ((size_t)b * 1024 + s0) * 256 + c0;
    #pragma unroll
    for (int r = 0; r < 4; ++r) {
        int s = ty + r * 8;
        ob[(size_t)s * 256 + tx] = f2bf(tile[tx][s]);
    }
}

// w [COUT][CIN][3][3] fp32 -> [COUT][9][CIN] bf16
__global__ __launch_bounds__(256) void pack_conv_w(
    const float* __restrict__ w, u16* __restrict__ out, int COUT, int CIN)
{
    int idx = blockIdx.x * 256 + threadIdx.x;
    if (idx >= COUT * CIN) return;
    int o = idx / CIN, c = idx - o * CIN;
    const float* g = w + (size_t)idx * 9;
    u16* ob = out + (size_t)o * 9 * CIN + c;
    #pragma unroll
    for (int t = 0; t < 9; ++t) ob[(size_t)t * CIN] = f2bf(g[t]);
}

// ---------------------------------------------------------------------------
// E GEMM: E[(b,l)][o][c] = sum_t w0b[o][l*1024+t] * tgt_l[b][c][t]
// tiles 128x128, BK=64, slot-XOR-swizzled LDS
// ---------------------------------------------------------------------------
__global__ __launch_bounds__(256) void e_gemm(
    const u16* __restrict__ w0b,    // [1024][2048]
    const u16* __restrict__ tgt2b,  // [8][256][1024]
    const u16* __restrict__ tgt3b,
    u16* __restrict__ E)            // [16][1024][256]
{
    __shared__ u16 ash[128 * 64];
    __shared__ u16 bsh[128 * 64];
    const int c0 = blockIdx.x * 128;
    const int o0 = blockIdx.y * 128;
    const int b  = blockIdx.z >> 1;
    const int l  = blockIdx.z & 1;
    const u16* tgt = (l == 0 ? tgt2b : tgt3b) + (size_t)b * 262144;
    const int tid = threadIdx.x, lane = tid & 63, wid = tid >> 6;
    const int wm = (wid >> 1) * 64, wn = (wid & 1) * 64;

    f32x4 acc[4][4];
    #pragma unroll
    for (int i = 0; i < 4; ++i)
        #pragma unroll
        for (int j = 0; j < 4; ++j) acc[i][j] = (f32x4){0.f, 0.f, 0.f, 0.f};

    for (int k0 = 0; k0 < 1024; k0 += 64) {
        #pragma unroll
        for (int p = 0; p < 4; ++p) {
            int idx = p * 256 + tid;
            int row = idx >> 3, s = idx & 7;
            *(bf16x8*)&ash[row * 64 + ((s ^ (row & 7)) << 3)] =
                *(const bf16x8*)(w0b + (size_t)(o0 + row) * 2048 + l * 1024 + k0 + s * 8);
            *(bf16x8*)&bsh[row * 64 + ((s ^ (row & 7)) << 3)] =
                *(const bf16x8*)(tgt + (size_t)(c0 + row) * 1024 + k0 + s * 8);
        }
        __syncthreads();
        #pragma unroll
        for (int kk = 0; kk < 2; ++kk) {
            bf16x8 af[4], bfr[4];
            #pragma unroll
            for (int i = 0; i < 4; ++i) {
                int row = wm + i * 16 + (lane & 15);
                int s = kk * 4 + (lane >> 4);
                af[i] = *(const bf16x8*)&ash[row * 64 + ((s ^ (row & 7)) << 3)];
                int rowb = wn + i * 16 + (lane & 15);
                bfr[i] = *(const bf16x8*)&bsh[rowb * 64 + ((s ^ (rowb & 7)) << 3)];
            }
            #pragma unroll
            for (int i = 0; i < 4; ++i)
                #pragma unroll
                for (int j = 0; j < 4; ++j)
                    acc[i][j] = MFMA16(af[i], bfr[j], acc[i][j]);
        }
        __syncthreads();
    }
    u16* Eb = E + ((size_t)blockIdx.z * 1024 + o0) * 256 + c0;
    #pragma unroll
    for (int i = 0; i < 4; ++i)
        #pragma unroll
        for (int j = 0; j < 4; ++j)
            #pragma unroll
            for (int r = 0; r < 4; ++r) {
                int m = wm + i * 16 + ((lane >> 4) << 2) + r;
                int n = wn + j * 16 + (lane & 15);
                Eb[(size_t)m * 256 + n] = f2bf(acc[i][j][r]);
            }
}

// ---------------------------------------------------------------------------
// x0 GEMM: x0T[b][s][o] = BN+leaky( sum_{l,c} srcT_l[b][s][c] * E[(b,l)][o][c] )
// M=s, N=o, K=512 (2 l x 4 chunks of 64)
// ---------------------------------------------------------------------------
__global__ __launch_bounds__(256) void x0_gemm(
    const u16* __restrict__ sA2,   // srcT or warpT layer2 [8][1024][256]
    const u16* __restrict__ sA3,
    const u16* __restrict__ E,     // [16][1024][256]
    const float* __restrict__ bng, const float* __restrict__ bnb,
    const float* __restrict__ bnm, const float* __restrict__ bnv,
    u16* __restrict__ x0T)         // [8][1024][1024]
{
    __shared__ u16 ash[128 * 64];
    __shared__ u16 bsh[128 * 64];
    const int o0 = blockIdx.x * 128;
    const int s0 = blockIdx.y * 128;
    const int b  = blockIdx.z;
    const int tid = threadIdx.x, lane = tid & 63, wid = tid >> 6;
    const int wm = (wid >> 1) * 64, wn = (wid & 1) * 64;

    f32x4 acc[4][4];
    #pragma unroll
    for (int i = 0; i < 4; ++i)
        #pragma unroll
        for (int j = 0; j < 4; ++j) acc[i][j] = (f32x4){0.f, 0.f, 0.f, 0.f};

    for (int kc = 0; kc < 8; ++kc) {
        const int l = kc >> 2;
        const int c0k = (kc & 3) * 64;
        const u16* sa = (l == 0 ? sA2 : sA3) + (size_t)b * 262144;
        const u16* eb = E + (size_t)((b << 1) + l) * 262144;
        #pragma unroll
        for (int p = 0; p < 4; ++p) {
            int idx = p * 256 + tid;
            int row = idx >> 3, s = idx & 7;
            *(bf16x8*)&ash[row * 64 + ((s ^ (row & 7)) << 3)] =
                *(const bf16x8*)(sa + (size_t)(s0 + row) * 256 + c0k + s * 8);
            *(bf16x8*)&bsh[row * 64 + ((s ^ (row & 7)) << 3)] =
                *(const bf16x8*)(eb + (size_t)(o0 + row) * 256 + c0k + s * 8);
        }
        __syncthreads();
        #pragma unroll
        for (int kk = 0; kk < 2; ++kk) {
            bf16x8 af[4], bfr[4];
            #pragma unroll
            for (int i = 0; i < 4; ++i) {
                int row = wm + i * 16 + (lane & 15);
                int s = kk * 4 + (lane >> 4);
                af[i] = *(const bf16x8*)&ash[row * 64 + ((s ^ (row & 7)) << 3)];
                int rowb = wn + i * 16 + (lane & 15);
                bfr[i] = *(const bf16x8*)&bsh[rowb * 64 + ((s ^ (rowb & 7)) << 3)];
            }
            #pragma unroll
            for (int i = 0; i < 4; ++i)
                #pragma unroll
                for (int j = 0; j < 4; ++j)
                    acc[i][j] = MFMA16(af[i], bfr[j], acc[i][j]);
        }
        __syncthreads();
    }
    #pragma unroll
    for (int j = 0; j < 4; ++j) {
        const int o = o0 + wn + j * 16 + (lane & 15);
        const float scv = bng[o] * rsqrtf(bnv[o] + BN_EPS);
        const float shv = bnb[o] - bnm[o] * scv;
        #pragma unroll
        for (int i = 0; i < 4; ++i)
            #pragma unroll
            for (int r = 0; r < 4; ++r) {
                int m = s0 + wm + i * 16 + ((lane >> 4) << 2) + r;
                float t = acc[i][j][r] * scv + shv;
                t = t >= 0.f ? t : SLOPE * t;
                x0T[((size_t)(b << 10) + m) * 1024 + o] = f2bf(t);
            }
    }
}

// ---------------------------------------------------------------------------
// 3x3 conv as implicit GEMM over taps.
// in: xT [8][1024][CIN] bf16, w: wpk [COUT][9][CIN] bf16
// out: xT [8][1024][COUT] bf16 (BN+leaky fused)
// block: 256 thr (4 waves), M=64 cout, N=256 spatial (8 rows), BK=32
// ---------------------------------------------------------------------------
template<int CIN, int COUT>
__global__ __launch_bounds__(256) void conv_gemm(
    const u16* __restrict__ xin,
    const u16* __restrict__ wpk,
    const float* __restrict__ bng, const float* __restrict__ bnb,
    const float* __restrict__ bnm, const float* __restrict__ bnv,
    u16* __restrict__ xout)
{
    __shared__ u16 ash[9 * 64 * 32];   // 36,864 B
    __shared__ u16 bsh[340 * 56];      // 38,080 B
    const int o0 = blockIdx.x * 64;
    const int y0 = blockIdx.y * 8;
    const int b  = blockIdx.z;
    const int tid = threadIdx.x, lane = tid & 63, wid = tid >> 6;
    const int wn = wid * 64;
    const u16* xb = xin + (size_t)b * 1024 * CIN;

    f32x4 acc[4][4];
    #pragma unroll
    for (int i = 0; i < 4; ++i)
        #pragma unroll
        for (int j = 0; j < 4; ++j) acc[i][j] = (f32x4){0.f, 0.f, 0.f, 0.f};

    for (int c0 = 0; c0 < CIN; c0 += 32) {
        // A: [9][64][32], 2-bit XOR slot swizzle
        #pragma unroll
        for (int p = 0; p < 9; ++p) {
            int idx = p * 256 + tid;
            int t = idx >> 8, row = (idx >> 2) & 63, s = idx & 3;
            *(bf16x8*)&ash[(t * 64 + row) * 32 + ((s ^ (row & 3)) << 3)] =
                *(const bf16x8*)(wpk + ((size_t)(o0 + row) * 9 + t) * CIN + c0 + s * 8);
        }
        // B: haloed [10 rows][34 cols][32], stride 56 (2-way banks)
        for (int idx = tid; idx < 1360; idx += 256) {
            int pos = idx >> 2, s = idx & 3;
            int py = pos / 34, px = pos - py * 34;
            int gy = y0 + py - 1, gx = px - 1;
            bf16x8 v = {0, 0, 0, 0, 0, 0, 0, 0};
            if (gy >= 0 && gy < 32 && gx >= 0 && gx < 32)
                v = *(const bf16x8*)&xb[(size_t)(gy * 32 + gx) * CIN + c0 + s * 8];
            *(bf16x8*)&bsh[pos * 56 + s * 8] = v;
        }
        __syncthreads();
        #pragma unroll
        for (int t = 0; t < 9; ++t) {
            const int dy = t / 3, dx = t - dy * 3;
            bf16x8 af[4], bfr[4];
            #pragma unroll
            for (int i = 0; i < 4; ++i) {
                int row = i * 16 + (lane & 15);
                int s = lane >> 4;
                af[i] = *(const bf16x8*)&ash[(t * 64 + row) * 32 + ((s ^ (row & 3)) << 3)];
            }
            #pragma unroll
            for (int j = 0; j < 4; ++j) {
                int n = wn + j * 16 + (lane & 15);
                int pos = ((n >> 5) + dy) * 34 + (n & 31) + dx;
                bfr[j] = *(const bf16x8*)&bsh[pos * 56 + ((lane >> 4) << 3)];
            }
            #pragma unroll
            for (int i = 0; i < 4; ++i)
                #pragma unroll
                for (int j = 0; j < 4; ++j)
                    acc[i][j] = MFMA16(af[i], bfr[j], acc[i][j]);
        }
        __syncthreads();
    }
    // epilogue: m=cout, n=spatial; packed 4x bf16 (8B) transposed stores
    #pragma unroll
    for (int i = 0; i < 4; ++i) {
        float scv[4], shv[4];
        #pragma unroll
        for (int r = 0; r < 4; ++r) {
            int o = o0 + i * 16 + ((lane >> 4) << 2) + r;
            float s = bng[o] * rsqrtf(bnv[o] + BN_EPS);
            scv[r] = s; shv[r] = bnb[o] - bnm[o] * s;
        }
        #pragma unroll
        for (int j = 0; j < 4; ++j) {
            int n = wn + j * 16 + (lane & 15);
            int sg = y0 * 32 + n;
            ushort4 pk;
            float t0 = acc[i][j][0] * scv[0] + shv[0]; t0 = t0 >= 0.f ? t0 : SLOPE * t0;
            float t1 = acc[i][j][1] * scv[1] + shv[1]; t1 = t1 >= 0.f ? t1 : SLOPE * t1;
            float t2 = acc[i][j][2] * scv[2] + shv[2]; t2 = t2 >= 0.f ? t2 : SLOPE * t2;
            float t3 = acc[i][j][3] * scv[3] + shv[3]; t3 = t3 >= 0.f ? t3 : SLOPE * t3;
            pk.x = f2bf(t0); pk.y = f2bf(t1); pk.z = f2bf(t2); pk.w = f2bf(t3);
            *(ushort4*)&xout[((size_t)(b * 1024 + sg)) * COUT + o0 + i * 16 + ((lane >> 4) << 2)] = pk;
        }
    }
}

// ---------------------------------------------------------------------------
// grid_sample on transposed layout: warpT[b][s][c] = bilinear blend of 4 rows
// one wave per (b,s); lane covers 4 channels
// ---------------------------------------------------------------------------
__global__ __launch_bounds__(64) void warp_kernel(
    const u16* __restrict__ srcT,   // [8][1024][256]
    const float* __restrict__ flow, // [8][1024][2]
    u16* __restrict__ outT)         // [8][1024][256]
{
    const int bs = blockIdx.x;
    const int b = bs >> 10;
    const float fx = flow[(size_t)bs * 2 + 0];
    const float fy = flow[(size_t)bs * 2 + 1];
    const float px = (fx + 1.f) * 15.5f;
    const float py = (fy + 1.f) * 15.5f;
    const float x0f = floorf(px), y0f = floorf(py);
    const int x0 = (int)x0f, y0 = (int)y0f;
    const float wx1 = px - x0f, wx0 = 1.f - wx1;
    const float wy1 = py - y0f, wy0 = 1.f - wy1;
    const int lane = threadIdx.x;
    const u16* sb = srcT + (size_t)b * 262144 + lane * 4;
    float a0 = 0.f, a1 = 0.f, a2 = 0.f, a3 = 0.f;
    #pragma unroll
    for (int cr = 0; cr < 4; ++cr) {
        const int xi = x0 + (cr & 1), yi = y0 + (cr >> 1);
        const float w = (cr == 0 ? wx0 * wy0 : cr == 1 ? wx1 * wy0 :
                         cr == 2 ? wx0 * wy1 : wx1 * wy1);
        if (xi >= 0 && xi < 32 && yi >= 0 && yi < 32) {
            const ushort4 v = *(const ushort4*)(sb + (size_t)(yi * 32 + xi) * 256);
            a0 += w * bf2f(v.x); a1 += w * bf2f(v.y);
            a2 += w * bf2f(v.z); a3 += w * bf2f(v.w);
        }
    }
    ushort4 o;
    o.x = f2bf(a0); o.y = f2bf(a1); o.z = f2bf(a2); o.w = f2bf(a3);
    *(ushort4*)(outT + (size_t)bs * 256 + lane * 4) = o;
}

// ---------------------------------------------------------------------------
// conv3 (1x1, 256->2) + bias + flow update; one wave per (b,s)
// ---------------------------------------------------------------------------
__global__ __launch_bounds__(256) void conv3_flow(
    const u16* __restrict__ x2T,   // [8][1024][256]
    const float* __restrict__ w3s, // [2][256]
    const float* __restrict__ b3s, // [2]
    float* __restrict__ flow, int add_ident)
{
    const int widx = blockIdx.x * 4 + (threadIdx.x >> 6);
    const int lane = threadIdx.x & 63;
    const ushort4 v = *(const ushort4*)&x2T[(size_t)widx * 256 + lane * 4];
    float a0 = 0.f, a1 = 0.f;
    const u16* vp = (const u16*)&v;
    #pragma unroll
    for (int j = 0; j < 4; ++j) {
        const float xv = bf2f(vp[j]);
        a0 += xv * w3s[lane * 4 + j];
        a1 += xv * w3s[256 + lane * 4 + j];
    }
    #pragma unroll
    for (int off = 32; off > 0; off >>= 1) {
        a0 += __shfl_down(a0, off);
        a1 += __shfl_down(a1, off);
    }
    if (lane == 0) {
        a0 += b3s[0]; a1 += b3s[1];
        float* f = flow + (size_t)widx * 2;
        if (add_ident) {
            const int s = widx & 1023;
            const int yy = s >> 5, xx = s & 31;
            f[0] = a0 + (-1.f + xx * (2.f / 31.f));
            f[1] = a1 + (-1.f + yy * (2.f / 31.f));
        } else {
            f[0] += a0;
            f[1] += a1;
        }
    }
}

__global__ __launch_bounds__(256) void copy_flow_kernel(
    const float* __restrict__ flow, float* __restrict__ out, int n)
{
    const int i = blockIdx.x * 256 + threadIdx.x;
    if (i < n) out[i] = flow[i];
}

// ---------------------------------------------------------------------------
extern "C" void kernel_launch(void* const* d_in, const int* in_sizes, int n_in,
                              void* d_out, int out_size, void* d_ws, size_t ws_size,
                              hipStream_t stream) {
    (void)in_sizes; (void)n_in; (void)ws_size;
    const float* src2 = (const float*)d_in[0];
    const float* src3 = (const float*)d_in[1];
    const float* tgt2 = (const float*)d_in[2];
    const float* tgt3 = (const float*)d_in[3];
    const float* w0   = (const float*)d_in[4];
    const float* w1   = (const float*)d_in[5];
    const float* w2   = (const float*)d_in[6];
    const float* w3   = (const float*)d_in[7];
    const float* b3   = (const float*)d_in[8];
    const float* bn0g = (const float*)d_in[9];
    const float* bn0b = (const float*)d_in[10];
    const float* bn0m = (const float*)d_in[11];
    const float* bn0v = (const float*)d_in[12];
    const float* bn1g = (const float*)d_in[13];
    const float* bn1b = (const float*)d_in[14];
    const float* bn1m = (const float*)d_in[15];
    const float* bn1v = (const float*)d_in[16];
    const float* bn2g = (const float*)d_in[17];
    const float* bn2b = (const float*)d_in[18];
    const float* bn2m = (const float*)d_in[19];
    const float* bn2v = (const float*)d_in[20];

    u16* ws = (u16*)d_ws;
    u16* tgt2b  = ws + OFF_TGT2B;
    u16* tgt3b  = ws + OFF_TGT3B;
    u16* srcT2  = ws + OFF_SRCT2;
    u16* srcT3  = ws + OFF_SRCT3;
    u16* warpT2 = ws + OFF_WARPT2;
    u16* warpT3 = ws + OFF_WARPT3;
    u16* w0b    = ws + OFF_W0B;
    u16* wpk1   = ws + OFF_WPK1;
    u16* wpk2   = ws + OFF_WPK2;
    u16* E      = ws + OFF_E;
    u16* x0T    = ws + OFF_X0T;
    u16* x1T    = ws + OFF_E;       // alias (E dead after x0_gemm)
    u16* x2T    = ws + OFF_WARPT2;  // alias (warp dead after x0_gemm)
    float* flow = (float*)(ws + OFF_FLOW);

    // one-time conversions
    cvt_kernel<<<2048, 256, 0, stream>>>(tgt2, tgt2b, 2097152);
    cvt_kernel<<<2048, 256, 0, stream>>>(tgt3, tgt3b, 2097152);
    transpose_cvt<<<dim3(32, 8, 8), 256, 0, stream>>>(src2, srcT2);
    transpose_cvt<<<dim3(32, 8, 8), 256, 0, stream>>>(src3, srcT3);

    for (int sc = 0; sc < 3; ++sc) {
        cvt_kernel<<<2048, 256, 0, stream>>>(w0 + (size_t)sc * 2097152, w0b, 2097152);
        pack_conv_w<<<2048, 256, 0, stream>>>(w1 + (size_t)sc * 4718592, wpk1, 512, 1024);
        pack_conv_w<<<512, 256, 0, stream>>>(w2 + (size_t)sc * 1179648, wpk2, 256, 512);

        const u16* a2 = srcT2;
        const u16* a3 = srcT3;
        if (sc > 0) {
            warp_kernel<<<8192, 64, 0, stream>>>(srcT2, flow, warpT2);
            warp_kernel<<<8192, 64, 0, stream>>>(srcT3, flow, warpT3);
            a2 = warpT2; a3 = warpT3;
        }
        e_gemm<<<dim3(2, 8, 16), 256, 0, stream>>>(w0b, tgt2b, tgt3b, E);
        x0_gemm<<<dim3(8, 8, 8), 256, 0, stream>>>(a2, a3, E,
            bn0g + sc * 1024, bn0b + sc * 1024, bn0m + sc * 1024, bn0v + sc * 1024, x0T);
        conv_gemm<1024, 512><<<dim3(8, 4, 8), 256, 0, stream>>>(x0T, wpk1,
            bn1g + sc * 512, bn1b + sc * 512, bn1m + sc * 512, bn1v + sc * 512, x1T);
        conv_gemm<512, 256><<<dim3(4, 4, 8), 256, 0, stream>>>(x1T, wpk2,
            bn2g + sc * 256, bn2b + sc * 256, bn2m + sc * 256, bn2v + sc * 256, x2T);
        conv3_flow<<<2048, 256, 0, stream>>>(x2T, w3 + sc * 512, b3 + sc * 2,
                                             flow, sc == 0 ? 1 : 0);
    }
    copy_flow_kernel<<<64, 256, 0, stream>>>(flow, (float*)d_out, out_size);
}

// Round 6
// 806.420 us; speedup vs baseline: 7.4345x; 1.1240x over previous
//
#include <hip/hip_runtime.h>
#include <cstdint>
#include <cstddef>

// ---------------------------------------------------------------------------
// MultiScaleSTN — bf16 MFMA pipeline, round 5: fix alias hazard from round 4
//   (zero_pads<512>(x1P) ran BEFORE x0_gemm, clobbering live E which x1P
//    aliases -> absmax 0.104. Moved to after x0_gemm. No other changes.)
//   E_l[b,o,c] = sum_t w0[o,l*1024+t] * tgt_l[b,c,t]            (MFMA GEMM)
//   x0P[b,p,o] = BN+leaky( sum_{l,c} srcT_l[b,s,c]*E[b,l,o,c] ) (MFMA GEMM,
//                 written into spatially PADDED [34x34] layout)
//   conv1/conv2: implicit GEMM, padded input -> contiguous halo staging,
//                64cout x (NT*32) spatial tiles, 2 blocks/CU
//   conv3 + flow + grid_sample: elementwise
// ---------------------------------------------------------------------------

typedef unsigned short u16;
using bf16x8 = __attribute__((ext_vector_type(8))) short;
using f32x4  = __attribute__((ext_vector_type(4))) float;

constexpr float BN_EPS = 1e-5f;
constexpr float SLOPE  = 0.1f;

__device__ __forceinline__ u16 f2bf(float f) {
    union { float f; uint32_t u; } c; c.f = f;
    uint32_t u = c.u;
    return (u16)((u + 0x7fffu + ((u >> 16) & 1u)) >> 16);
}
__device__ __forceinline__ float bf2f(u16 h) {
    union { uint32_t u; float f; } c; c.u = ((uint32_t)h) << 16;
    return c.f;
}

#define MFMA16(a, b, c) __builtin_amdgcn_mfma_f32_16x16x32_bf16(a, b, c, 0, 0, 0)

// workspace offsets in u16 units (total 65.4 MB)
constexpr size_t OFF_TGT2B  = 0;          // [8][256][1024]
constexpr size_t OFF_TGT3B  = 2097152;
constexpr size_t OFF_SRCT2  = 4194304;    // [8][1024][256]
constexpr size_t OFF_SRCT3  = 6291456;
constexpr size_t OFF_WARPT2 = 8388608;    // [8][1024][256]; x2T aliases
constexpr size_t OFF_WARPT3 = 10485760;
constexpr size_t OFF_WPK1   = 12582912;   // [512][9][1024]
constexpr size_t OFF_WPK2   = 17301504;   // [256][9][512]
constexpr size_t OFF_EX1    = 18481152;   // E [16][1024][256] (4,194,304) and
                                          // X1P [8][1156][512] (4,734,976) alias
constexpr size_t OFF_X0P    = 23216128;   // [8][1156][1024] (9,469,952);
                                          // W0B [1024][2048] aliases its start
constexpr size_t OFF_FLOW   = 32686080;   // fp32 [8][1024][2] (32,768 u16)
// alias ledger (per scale, single stream, in launch order):
//   cvt -> w0b (x0P head; prev x0P dead)           [writes w0b]
//   e_gemm: reads w0b, writes E                    [E live]
//   zero_pads<1024>(x0P): pads only; overlaps w0b (dead). E untouched
//   x0_gemm: reads E + warp/src, writes x0P interior (kills w0b)
//   zero_pads<512>(x1P): overlaps E (NOW dead)     [x1P pads zeroed]
//   conv1: reads x0P (all pos), writes x1P interior (kills E fully)
//   conv2: reads x1P (all pos), writes x2T (aliases warpT2, dead)
//   conv3_flow: reads x2T, updates flow

// ---------------------------------------------------------------------------
__global__ __launch_bounds__(256) void cvt_kernel(
    const float* __restrict__ in, u16* __restrict__ out, int n)
{
    int i = (blockIdx.x * 256 + threadIdx.x) * 4;
    if (i + 3 < n) {
        float4 v = *(const float4*)(in + i);
        ushort4 o;
        o.x = f2bf(v.x); o.y = f2bf(v.y); o.z = f2bf(v.z); o.w = f2bf(v.w);
        *(ushort4*)(out + i) = o;
    }
}

// fp32 [8][256][1024] -> bf16 [8][1024][256] (transpose)
__global__ __launch_bounds__(256) void transpose_cvt(
    const float* __restrict__ in, u16* __restrict__ out)
{
    __shared__ float tile[32][33];
    const int s0 = blockIdx.x * 32;
    const int c0 = blockIdx.y * 32;
    const int b  = blockIdx.z;
    const int tid = threadIdx.x;
    const int tx = tid & 31, ty = tid >> 5;
    const float* ib = in + ((size_t)b * 256 + c0) * 1024 + s0;
    #pragma unroll
    for (int r = 0; r < 4; ++r)
        tile[ty + r * 8][tx] = ib[(size_t)(ty + r * 8) * 1024 + tx];
    __syncthreads();
    u16* ob = out + ((size_t)b * 1024 + s0) * 256 + c0;
    #pragma unroll
    for (int r = 0; r < 4; ++r) {
        int s = ty + r * 8;
        ob[(size_t)s * 256 + tx] = f2bf(tile[tx][s]);
    }
}

// w [COUT][CIN][3][3] fp32 -> [COUT][9][CIN] bf16
__global__ __launch_bounds__(256) void pack_conv_w(
    const float* __restrict__ w, u16* __restrict__ out, int COUT, int CIN)
{
    int idx = blockIdx.x * 256 + threadIdx.x;
    if (idx >= COUT * CIN) return;
    int o = idx / CIN, c = idx - o * CIN;
    const float* g = w + (size_t)idx * 9;
    u16* ob = out + (size_t)o * 9 * CIN + c;
    #pragma unroll
    for (int t = 0; t < 9; ++t) ob[(size_t)t * CIN] = f2bf(g[t]);
}

// zero the pad ring of a padded activation tensor [8][34*34][C]
template<int C>
__global__ __launch_bounds__(256) void zero_pads(u16* __restrict__ xP)
{
    constexpr int NC = C / 8;
    int idx = blockIdx.x * 256 + threadIdx.x;
    if (idx >= 8 * 132 * NC) return;
    int c8  = idx & (NC - 1);
    int rem = idx / NC;
    int b = rem / 132, j = rem - b * 132;
    int pos;
    if (j < 34)      pos = j;                                  // row 0
    else if (j < 68) pos = 1122 + (j - 34);                    // row 33
    else { int k = j - 68; pos = ((k >> 1) + 1) * 34 + (k & 1) * 33; }  // cols
    *(bf16x8*)&xP[((size_t)b * 1156 + pos) * C + c8 * 8] = (bf16x8){0,0,0,0,0,0,0,0};
}

// ---------------------------------------------------------------------------
// E GEMM: E[(b,l)][o][c] = sum_t w0b[o][l*1024+t] * tgt_l[b][c][t]
// tiles 128x128, BK=64, slot-XOR-swizzled LDS
// ---------------------------------------------------------------------------
__global__ __launch_bounds__(256) void e_gemm(
    const u16* __restrict__ w0b,    // [1024][2048]
    const u16* __restrict__ tgt2b,  // [8][256][1024]
    const u16* __restrict__ tgt3b,
    u16* __restrict__ E)            // [16][1024][256]
{
    __shared__ u16 ash[128 * 64];
    __shared__ u16 bsh[128 * 64];
    const int c0 = blockIdx.x * 128;
    const int o0 = blockIdx.y * 128;
    const int b  = blockIdx.z >> 1;
    const int l  = blockIdx.z & 1;
    const u16* tgt = (l == 0 ? tgt2b : tgt3b) + (size_t)b * 262144;
    const int tid = threadIdx.x, lane = tid & 63, wid = tid >> 6;
    const int wm = (wid >> 1) * 64, wn = (wid & 1) * 64;

    f32x4 acc[4][4];
    #pragma unroll
    for (int i = 0; i < 4; ++i)
        #pragma unroll
        for (int j = 0; j < 4; ++j) acc[i][j] = (f32x4){0.f, 0.f, 0.f, 0.f};

    for (int k0 = 0; k0 < 1024; k0 += 64) {
        #pragma unroll
        for (int p = 0; p < 4; ++p) {
            int idx = p * 256 + tid;
            int row = idx >> 3, s = idx & 7;
            *(bf16x8*)&ash[row * 64 + ((s ^ (row & 7)) << 3)] =
                *(const bf16x8*)(w0b + (size_t)(o0 + row) * 2048 + l * 1024 + k0 + s * 8);
            *(bf16x8*)&bsh[row * 64 + ((s ^ (row & 7)) << 3)] =
                *(const bf16x8*)(tgt + (size_t)(c0 + row) * 1024 + k0 + s * 8);
        }
        __syncthreads();
        #pragma unroll
        for (int kk = 0; kk < 2; ++kk) {
            bf16x8 af[4], bfr[4];
            #pragma unroll
            for (int i = 0; i < 4; ++i) {
                int row = wm + i * 16 + (lane & 15);
                int s = kk * 4 + (lane >> 4);
                af[i] = *(const bf16x8*)&ash[row * 64 + ((s ^ (row & 7)) << 3)];
                int rowb = wn + i * 16 + (lane & 15);
                bfr[i] = *(const bf16x8*)&bsh[rowb * 64 + ((s ^ (rowb & 7)) << 3)];
            }
            #pragma unroll
            for (int i = 0; i < 4; ++i)
                #pragma unroll
                for (int j = 0; j < 4; ++j)
                    acc[i][j] = MFMA16(af[i], bfr[j], acc[i][j]);
        }
        __syncthreads();
    }
    u16* Eb = E + ((size_t)blockIdx.z * 1024 + o0) * 256 + c0;
    #pragma unroll
    for (int i = 0; i < 4; ++i)
        #pragma unroll
        for (int j = 0; j < 4; ++j)
            #pragma unroll
            for (int r = 0; r < 4; ++r) {
                int m = wm + i * 16 + ((lane >> 4) << 2) + r;
                int n = wn + j * 16 + (lane & 15);
                Eb[(size_t)m * 256 + n] = f2bf(acc[i][j][r]);
            }
}

// ---------------------------------------------------------------------------
// x0 GEMM: x0P[b][pad(s)][o] = BN+leaky( sum_{l,c} srcT_l[b][s][c]*E[(b,l)][o][c] )
// ---------------------------------------------------------------------------
__global__ __launch_bounds__(256) void x0_gemm(
    const u16* __restrict__ sA2,   // srcT or warpT layer2 [8][1024][256]
    const u16* __restrict__ sA3,
    const u16* __restrict__ E,     // [16][1024][256]
    const float* __restrict__ bng, const float* __restrict__ bnb,
    const float* __restrict__ bnm, const float* __restrict__ bnv,
    u16* __restrict__ x0P)         // [8][1156][1024] padded
{
    __shared__ u16 ash[128 * 64];
    __shared__ u16 bsh[128 * 64];
    const int o0 = blockIdx.x * 128;
    const int s0 = blockIdx.y * 128;
    const int b  = blockIdx.z;
    const int tid = threadIdx.x, lane = tid & 63, wid = tid >> 6;
    const int wm = (wid >> 1) * 64, wn = (wid & 1) * 64;

    f32x4 acc[4][4];
    #pragma unroll
    for (int i = 0; i < 4; ++i)
        #pragma unroll
        for (int j = 0; j < 4; ++j) acc[i][j] = (f32x4){0.f, 0.f, 0.f, 0.f};

    for (int kc = 0; kc < 8; ++kc) {
        const int l = kc >> 2;
        const int c0k = (kc & 3) * 64;
        const u16* sa = (l == 0 ? sA2 : sA3) + (size_t)b * 262144;
        const u16* eb = E + (size_t)((b << 1) + l) * 262144;
        #pragma unroll
        for (int p = 0; p < 4; ++p) {
            int idx = p * 256 + tid;
            int row = idx >> 3, s = idx & 7;
            *(bf16x8*)&ash[row * 64 + ((s ^ (row & 7)) << 3)] =
                *(const bf16x8*)(sa + (size_t)(s0 + row) * 256 + c0k + s * 8);
            *(bf16x8*)&bsh[row * 64 + ((s ^ (row & 7)) << 3)] =
                *(const bf16x8*)(eb + (size_t)(o0 + row) * 256 + c0k + s * 8);
        }
        __syncthreads();
        #pragma unroll
        for (int kk = 0; kk < 2; ++kk) {
            bf16x8 af[4], bfr[4];
            #pragma unroll
            for (int i = 0; i < 4; ++i) {
                int row = wm + i * 16 + (lane & 15);
                int s = kk * 4 + (lane >> 4);
                af[i] = *(const bf16x8*)&ash[row * 64 + ((s ^ (row & 7)) << 3)];
                int rowb = wn + i * 16 + (lane & 15);
                bfr[i] = *(const bf16x8*)&bsh[rowb * 64 + ((s ^ (rowb & 7)) << 3)];
            }
            #pragma unroll
            for (int i = 0; i < 4; ++i)
                #pragma unroll
                for (int j = 0; j < 4; ++j)
                    acc[i][j] = MFMA16(af[i], bfr[j], acc[i][j]);
        }
        __syncthreads();
    }
    #pragma unroll
    for (int j = 0; j < 4; ++j) {
        const int o = o0 + wn + j * 16 + (lane & 15);
        const float scv = bng[o] * rsqrtf(bnv[o] + BN_EPS);
        const float shv = bnb[o] - bnm[o] * scv;
        #pragma unroll
        for (int i = 0; i < 4; ++i)
            #pragma unroll
            for (int r = 0; r < 4; ++r) {
                int m = s0 + wm + i * 16 + ((lane >> 4) << 2) + r;
                float t = acc[i][j][r] * scv + shv;
                t = t >= 0.f ? t : SLOPE * t;
                size_t sp = (size_t)b * 1156 + ((m >> 5) + 1) * 34 + (m & 31) + 1;
                x0P[sp * 1024 + o] = f2bf(t);
            }
    }
}

// ---------------------------------------------------------------------------
// 3x3 conv as implicit GEMM over taps, PADDED input.
// in: xP [8][1156][CIN], w: wpk [COUT][9][CIN]
// tile: 64 cout x (NT*32) spatial; 4 waves, wave = 64 x (NT*8); BK=32 cin
// LDS: A [9][64][32] swizzled (2-way max); B [(NT+2)*34 pos][stride 36] (2-way)
// ---------------------------------------------------------------------------
template<int CIN, int COUT, int NT, bool PADOUT>
__global__ __launch_bounds__(256) void conv_gemm(
    const u16* __restrict__ xinP,
    const u16* __restrict__ wpk,
    const float* __restrict__ bng, const float* __restrict__ bnb,
    const float* __restrict__ bnm, const float* __restrict__ bnv,
    u16* __restrict__ xout)
{
    constexpr int NPOS = (NT + 2) * 34;
    constexpr int JT = NT / 2;
    __shared__ u16 ash[9 * 64 * 32];
    __shared__ u16 bsh[NPOS * 36];
    const int o0 = blockIdx.x * 64;
    const int y0 = blockIdx.y * NT;
    const int b  = blockIdx.z;
    const int tid = threadIdx.x, lane = tid & 63, wid = tid >> 6;
    const int wn = wid * (NT * 8);
    const u16* xpb = xinP + ((size_t)b * 1156 + y0 * 34) * CIN;

    f32x4 acc[4][JT];
    #pragma unroll
    for (int i = 0; i < 4; ++i)
        #pragma unroll
        for (int j = 0; j < JT; ++j) acc[i][j] = (f32x4){0.f, 0.f, 0.f, 0.f};

    for (int c0 = 0; c0 < CIN; c0 += 32) {
        // A: [tap][64 rows][32 cin], slot' = s ^ ((row>>1)&3) -> 2-way banks
        #pragma unroll
        for (int p = 0; p < 9; ++p) {
            int idx = p * 256 + tid;
            int row = (idx >> 2) & 63, s = idx & 3;
            *(bf16x8*)&ash[((p * 64 + row) << 5) + ((s ^ ((row >> 1) & 3)) << 3)] =
                *(const bf16x8*)(wpk + ((size_t)(o0 + row) * 9 + p) * CIN + c0 + s * 8);
        }
        // B: contiguous padded rows y0..y0+NT+1, stride 36 elem (72B) -> 2-way
        for (int idx = tid; idx < NPOS * 4; idx += 256) {
            int pos = idx >> 2, s = idx & 3;
            *(bf16x8*)&bsh[pos * 36 + s * 8] =
                *(const bf16x8*)(xpb + (size_t)pos * CIN + c0 + s * 8);
        }
        __syncthreads();
        #pragma unroll
        for (int t = 0; t < 9; ++t) {
            const int dy = t / 3, dx = t - dy * 3;
            bf16x8 af[4], bfr[JT];
            #pragma unroll
            for (int i = 0; i < 4; ++i) {
                int row = i * 16 + (lane & 15);
                af[i] = *(const bf16x8*)&ash[((t * 64 + row) << 5) +
                                             (((lane >> 4) ^ ((row >> 1) & 3)) << 3)];
            }
            #pragma unroll
            for (int j = 0; j < JT; ++j) {
                int n = wn + j * 16 + (lane & 15);
                int pos = ((n >> 5) + dy) * 34 + (n & 31) + dx;
                bfr[j] = *(const bf16x8*)&bsh[pos * 36 + ((lane >> 4) << 3)];
            }
            #pragma unroll
            for (int i = 0; i < 4; ++i)
                #pragma unroll
                for (int j = 0; j < JT; ++j)
                    acc[i][j] = MFMA16(af[i], bfr[j], acc[i][j]);
        }
        __syncthreads();
    }
    #pragma unroll
    for (int i = 0; i < 4; ++i) {
        float scv[4], shv[4];
        #pragma unroll
        for (int r = 0; r < 4; ++r) {
            int o = o0 + i * 16 + ((lane >> 4) << 2) + r;
            float s = bng[o] * rsqrtf(bnv[o] + BN_EPS);
            scv[r] = s; shv[r] = bnb[o] - bnm[o] * s;
        }
        #pragma unroll
        for (int j = 0; j < JT; ++j) {
            int n = wn + j * 16 + (lane & 15);
            int yg = y0 + (n >> 5), xg = n & 31;
            size_t sp = PADOUT ? ((size_t)b * 1156 + (size_t)(yg + 1) * 34 + xg + 1)
                               : ((size_t)b * 1024 + (size_t)yg * 32 + xg);
            ushort4 pk;
            float t0 = acc[i][j][0] * scv[0] + shv[0]; t0 = t0 >= 0.f ? t0 : SLOPE * t0;
            float t1 = acc[i][j][1] * scv[1] + shv[1]; t1 = t1 >= 0.f ? t1 : SLOPE * t1;
            float t2 = acc[i][j][2] * scv[2] + shv[2]; t2 = t2 >= 0.f ? t2 : SLOPE * t2;
            float t3 = acc[i][j][3] * scv[3] + shv[3]; t3 = t3 >= 0.f ? t3 : SLOPE * t3;
            pk.x = f2bf(t0); pk.y = f2bf(t1); pk.z = f2bf(t2); pk.w = f2bf(t3);
            *(ushort4*)&xout[sp * COUT + o0 + i * 16 + ((lane >> 4) << 2)] = pk;
        }
    }
}

// ---------------------------------------------------------------------------
// grid_sample on transposed layout
// ---------------------------------------------------------------------------
__global__ __launch_bounds__(64) void warp_kernel(
    const u16* __restrict__ srcT,   // [8][1024][256]
    const float* __restrict__ flow, // [8][1024][2]
    u16* __restrict__ outT)         // [8][1024][256]
{
    const int bs = blockIdx.x;
    const int b = bs >> 10;
    const float fx = flow[(size_t)bs * 2 + 0];
    const float fy = flow[(size_t)bs * 2 + 1];
    const float px = (fx + 1.f) * 15.5f;
    const float py = (fy + 1.f) * 15.5f;
    const float x0f = floorf(px), y0f = floorf(py);
    const int x0 = (int)x0f, y0 = (int)y0f;
    const float wx1 = px - x0f, wx0 = 1.f - wx1;
    const float wy1 = py - y0f, wy0 = 1.f - wy1;
    const int lane = threadIdx.x;
    const u16* sb = srcT + (size_t)b * 262144 + lane * 4;
    float a0 = 0.f, a1 = 0.f, a2 = 0.f, a3 = 0.f;
    #pragma unroll
    for (int cr = 0; cr < 4; ++cr) {
        const int xi = x0 + (cr & 1), yi = y0 + (cr >> 1);
        const float w = (cr == 0 ? wx0 * wy0 : cr == 1 ? wx1 * wy0 :
                         cr == 2 ? wx0 * wy1 : wx1 * wy1);
        if (xi >= 0 && xi < 32 && yi >= 0 && yi < 32) {
            const ushort4 v = *(const ushort4*)(sb + (size_t)(yi * 32 + xi) * 256);
            a0 += w * bf2f(v.x); a1 += w * bf2f(v.y);
            a2 += w * bf2f(v.z); a3 += w * bf2f(v.w);
        }
    }
    ushort4 o;
    o.x = f2bf(a0); o.y = f2bf(a1); o.z = f2bf(a2); o.w = f2bf(a3);
    *(ushort4*)(outT + (size_t)bs * 256 + lane * 4) = o;
}

// ---------------------------------------------------------------------------
// conv3 (1x1, 256->2) + bias + flow update; one wave per (b,s)
// ---------------------------------------------------------------------------
__global__ __launch_bounds__(256) void conv3_flow(
    const u16* __restrict__ x2T,   // [8][1024][256]
    const float* __restrict__ w3s, // [2][256]
    const float* __restrict__ b3s, // [2]
    float* __restrict__ flow, int add_ident)
{
    const int widx = blockIdx.x * 4 + (threadIdx.x >> 6);
    const int lane = threadIdx.x & 63;
    const ushort4 v = *(const ushort4*)&x2T[(size_t)widx * 256 + lane * 4];
    float a0 = 0.f, a1 = 0.f;
    const u16* vp = (const u16*)&v;
    #pragma unroll
    for (int j = 0; j < 4; ++j) {
        const float xv = bf2f(vp[j]);
        a0 += xv * w3s[lane * 4 + j];
        a1 += xv * w3s[256 + lane * 4 + j];
    }
    #pragma unroll
    for (int off = 32; off > 0; off >>= 1) {
        a0 += __shfl_down(a0, off);
        a1 += __shfl_down(a1, off);
    }
    if (lane == 0) {
        a0 += b3s[0]; a1 += b3s[1];
        float* f = flow + (size_t)widx * 2;
        if (add_ident) {
            const int s = widx & 1023;
            const int yy = s >> 5, xx = s & 31;
            f[0] = a0 + (-1.f + xx * (2.f / 31.f));
            f[1] = a1 + (-1.f + yy * (2.f / 31.f));
        } else {
            f[0] += a0;
            f[1] += a1;
        }
    }
}

__global__ __launch_bounds__(256) void copy_flow_kernel(
    const float* __restrict__ flow, float* __restrict__ out, int n)
{
    const int i = blockIdx.x * 256 + threadIdx.x;
    if (i < n) out[i] = flow[i];
}

// ---------------------------------------------------------------------------
extern "C" void kernel_launch(void* const* d_in, const int* in_sizes, int n_in,
                              void* d_out, int out_size, void* d_ws, size_t ws_size,
                              hipStream_t stream) {
    (void)in_sizes; (void)n_in; (void)ws_size;
    const float* src2 = (const float*)d_in[0];
    const float* src3 = (const float*)d_in[1];
    const float* tgt2 = (const float*)d_in[2];
    const float* tgt3 = (const float*)d_in[3];
    const float* w0   = (const float*)d_in[4];
    const float* w1   = (const float*)d_in[5];
    const float* w2   = (const float*)d_in[6];
    const float* w3   = (const float*)d_in[7];
    const float* b3   = (const float*)d_in[8];
    const float* bn0g = (const float*)d_in[9];
    const float* bn0b = (const float*)d_in[10];
    const float* bn0m = (const float*)d_in[11];
    const float* bn0v = (const float*)d_in[12];
    const float* bn1g = (const float*)d_in[13];
    const float* bn1b = (const float*)d_in[14];
    const float* bn1m = (const float*)d_in[15];
    const float* bn1v = (const float*)d_in[16];
    const float* bn2g = (const float*)d_in[17];
    const float* bn2b = (const float*)d_in[18];
    const float* bn2m = (const float*)d_in[19];
    const float* bn2v = (const float*)d_in[20];

    u16* ws = (u16*)d_ws;
    u16* tgt2b  = ws + OFF_TGT2B;
    u16* tgt3b  = ws + OFF_TGT3B;
    u16* srcT2  = ws + OFF_SRCT2;
    u16* srcT3  = ws + OFF_SRCT3;
    u16* warpT2 = ws + OFF_WARPT2;
    u16* warpT3 = ws + OFF_WARPT3;
    u16* wpk1   = ws + OFF_WPK1;
    u16* wpk2   = ws + OFF_WPK2;
    u16* E      = ws + OFF_EX1;
    u16* x1P    = ws + OFF_EX1;     // alias: E dead after x0_gemm
    u16* x0P    = ws + OFF_X0P;
    u16* w0b    = ws + OFF_X0P;     // alias: w0b dead after e_gemm
    u16* x2T    = ws + OFF_WARPT2;  // alias: warpT2 dead after x0_gemm
    float* flow = (float*)(ws + OFF_FLOW);

    // one-time conversions
    cvt_kernel<<<2048, 256, 0, stream>>>(tgt2, tgt2b, 2097152);
    cvt_kernel<<<2048, 256, 0, stream>>>(tgt3, tgt3b, 2097152);
    transpose_cvt<<<dim3(32, 8, 8), 256, 0, stream>>>(src2, srcT2);
    transpose_cvt<<<dim3(32, 8, 8), 256, 0, stream>>>(src3, srcT3);

    for (int sc = 0; sc < 3; ++sc) {
        cvt_kernel<<<2048, 256, 0, stream>>>(w0 + (size_t)sc * 2097152, w0b, 2097152);
        pack_conv_w<<<2048, 256, 0, stream>>>(w1 + (size_t)sc * 4718592, wpk1, 512, 1024);
        pack_conv_w<<<512, 256, 0, stream>>>(w2 + (size_t)sc * 1179648, wpk2, 256, 512);

        const u16* a2 = srcT2;
        const u16* a3 = srcT3;
        if (sc > 0) {
            warp_kernel<<<8192, 64, 0, stream>>>(srcT2, flow, warpT2);
            warp_kernel<<<8192, 64, 0, stream>>>(srcT3, flow, warpT3);
            a2 = warpT2; a3 = warpT3;
        }
        e_gemm<<<dim3(2, 8, 16), 256, 0, stream>>>(w0b, tgt2b, tgt3b, E);
        // x0P pads: safe here (x0P aliases only w0b, dead after e_gemm)
        zero_pads<1024><<<528, 256, 0, stream>>>(x0P);
        x0_gemm<<<dim3(8, 8, 8), 256, 0, stream>>>(a2, a3, E,
            bn0g + sc * 1024, bn0b + sc * 1024, bn0m + sc * 1024, bn0v + sc * 1024, x0P);
        // x1P pads: MUST be after x0_gemm (x1P aliases E; r4 bug was here)
        zero_pads<512><<<264, 256, 0, stream>>>(x1P);
        conv_gemm<1024, 512, 4, true><<<dim3(8, 8, 8), 256, 0, stream>>>(x0P, wpk1,
            bn1g + sc * 512, bn1b + sc * 512, bn1m + sc * 512, bn1v + sc * 512, x1P);
        conv_gemm<512, 256, 2, false><<<dim3(4, 16, 8), 256, 0, stream>>>(x1P, wpk2,
            bn2g + sc * 256, bn2b + sc * 256, bn2m + sc * 256, bn2v + sc * 256, x2T);
        conv3_flow<<<2048, 256, 0, stream>>>(x2T, w3 + sc * 512, b3 + sc * 2,
                                             flow, sc == 0 ? 1 : 0);
    }
    copy_flow_kernel<<<64, 256, 0, stream>>>(flow, (float*)d_out, out_size);
}

// Round 9
// 735.973 us; speedup vs baseline: 8.1461x; 1.0957x over previous
//
#include <hip/hip_runtime.h>
#include <cstdint>
#include <cstddef>

// ---------------------------------------------------------------------------
// MultiScaleSTN — bf16 MFMA pipeline, round 6 (r8 resubmit; r7+r8 benches were
// infra failures: GPUAcquisitionTimeout, kernel never ran)
// r5 counters: conv1 ≈ conv2 ≈ 115us (6 dispatches = 86% of 806us total);
// MfmaUtil 28%, VALU 11% -> 60% idle = exposed staging latency per chunk.
// This version (conv_gemm only):
//   (a) T14 register prefetch: global loads for chunk c+1 issued before
//       compute of chunk c (held in VGPRs, ds_write after barrier)
//   (b) conv2: MB=32 cout/block -> grid 512 (2 blocks/CU), A-stage halved
// ---------------------------------------------------------------------------

typedef unsigned short u16;
using bf16x8 = __attribute__((ext_vector_type(8))) short;
using f32x4  = __attribute__((ext_vector_type(4))) float;

constexpr float BN_EPS = 1e-5f;
constexpr float SLOPE  = 0.1f;

__device__ __forceinline__ u16 f2bf(float f) {
    union { float f; uint32_t u; } c; c.f = f;
    uint32_t u = c.u;
    return (u16)((u + 0x7fffu + ((u >> 16) & 1u)) >> 16);
}
__device__ __forceinline__ float bf2f(u16 h) {
    union { uint32_t u; float f; } c; c.u = ((uint32_t)h) << 16;
    return c.f;
}

#define MFMA16(a, b, c) __builtin_amdgcn_mfma_f32_16x16x32_bf16(a, b, c, 0, 0, 0)

// workspace offsets in u16 units (total 65.4 MB)
constexpr size_t OFF_TGT2B  = 0;          // [8][256][1024]
constexpr size_t OFF_TGT3B  = 2097152;
constexpr size_t OFF_SRCT2  = 4194304;    // [8][1024][256]
constexpr size_t OFF_SRCT3  = 6291456;
constexpr size_t OFF_WARPT2 = 8388608;    // [8][1024][256]; x2T aliases
constexpr size_t OFF_WARPT3 = 10485760;
constexpr size_t OFF_WPK1   = 12582912;   // [512][9][1024]
constexpr size_t OFF_WPK2   = 17301504;   // [256][9][512]
constexpr size_t OFF_EX1    = 18481152;   // E [16][1024][256] / X1P [8][1156][512] alias
constexpr size_t OFF_X0P    = 23216128;   // X0P [8][1156][1024]; W0B aliases head
constexpr size_t OFF_FLOW   = 32686080;   // fp32 [8][1024][2]
// alias ledger (per scale, launch order):
//   cvt -> w0b ; e_gemm reads w0b writes E ; zero_pads<1024>(x0P) [w0b dead]
//   x0_gemm reads E writes x0P ; zero_pads<512>(x1P) [E dead - r4 bug fixed r5]
//   conv1 reads x0P writes x1P ; conv2 reads x1P writes x2T(warpT2 dead)
//   conv3_flow reads x2T

// ---------------------------------------------------------------------------
__global__ __launch_bounds__(256) void cvt_kernel(
    const float* __restrict__ in, u16* __restrict__ out, int n)
{
    int i = (blockIdx.x * 256 + threadIdx.x) * 4;
    if (i + 3 < n) {
        float4 v = *(const float4*)(in + i);
        ushort4 o;
        o.x = f2bf(v.x); o.y = f2bf(v.y); o.z = f2bf(v.z); o.w = f2bf(v.w);
        *(ushort4*)(out + i) = o;
    }
}

// fp32 [8][256][1024] -> bf16 [8][1024][256] (transpose)
__global__ __launch_bounds__(256) void transpose_cvt(
    const float* __restrict__ in, u16* __restrict__ out)
{
    __shared__ float tile[32][33];
    const int s0 = blockIdx.x * 32;
    const int c0 = blockIdx.y * 32;
    const int b  = blockIdx.z;
    const int tid = threadIdx.x;
    const int tx = tid & 31, ty = tid >> 5;
    const float* ib = in + ((size_t)b * 256 + c0) * 1024 + s0;
    #pragma unroll
    for (int r = 0; r < 4; ++r)
        tile[ty + r * 8][tx] = ib[(size_t)(ty + r * 8) * 1024 + tx];
    __syncthreads();
    u16* ob = out + ((size_t)b * 1024 + s0) * 256 + c0;
    #pragma unroll
    for (int r = 0; r < 4; ++r) {
        int s = ty + r * 8;
        ob[(size_t)s * 256 + tx] = f2bf(tile[tx][s]);
    }
}

// w [COUT][CIN][3][3] fp32 -> [COUT][9][CIN] bf16
__global__ __launch_bounds__(256) void pack_conv_w(
    const float* __restrict__ w, u16* __restrict__ out, int COUT, int CIN)
{
    int idx = blockIdx.x * 256 + threadIdx.x;
    if (idx >= COUT * CIN) return;
    int o = idx / CIN, c = idx - o * CIN;
    const float* g = w + (size_t)idx * 9;
    u16* ob = out + (size_t)o * 9 * CIN + c;
    #pragma unroll
    for (int t = 0; t < 9; ++t) ob[(size_t)t * CIN] = f2bf(g[t]);
}

// zero the pad ring of a padded activation tensor [8][34*34][C]
template<int C>
__global__ __launch_bounds__(256) void zero_pads(u16* __restrict__ xP)
{
    constexpr int NC = C / 8;
    int idx = blockIdx.x * 256 + threadIdx.x;
    if (idx >= 8 * 132 * NC) return;
    int c8  = idx & (NC - 1);
    int rem = idx / NC;
    int b = rem / 132, j = rem - b * 132;
    int pos;
    if (j < 34)      pos = j;                                  // row 0
    else if (j < 68) pos = 1122 + (j - 34);                    // row 33
    else { int k = j - 68; pos = ((k >> 1) + 1) * 34 + (k & 1) * 33; }  // cols
    *(bf16x8*)&xP[((size_t)b * 1156 + pos) * C + c8 * 8] = (bf16x8){0,0,0,0,0,0,0,0};
}

// ---------------------------------------------------------------------------
// E GEMM: E[(b,l)][o][c] = sum_t w0b[o][l*1024+t] * tgt_l[b][c][t]
// tiles 128x128, BK=64, slot-XOR-swizzled LDS
// ---------------------------------------------------------------------------
__global__ __launch_bounds__(256) void e_gemm(
    const u16* __restrict__ w0b,    // [1024][2048]
    const u16* __restrict__ tgt2b,  // [8][256][1024]
    const u16* __restrict__ tgt3b,
    u16* __restrict__ E)            // [16][1024][256]
{
    __shared__ u16 ash[128 * 64];
    __shared__ u16 bsh[128 * 64];
    const int c0 = blockIdx.x * 128;
    const int o0 = blockIdx.y * 128;
    const int b  = blockIdx.z >> 1;
    const int l  = blockIdx.z & 1;
    const u16* tgt = (l == 0 ? tgt2b : tgt3b) + (size_t)b * 262144;
    const int tid = threadIdx.x, lane = tid & 63, wid = tid >> 6;
    const int wm = (wid >> 1) * 64, wn = (wid & 1) * 64;

    f32x4 acc[4][4];
    #pragma unroll
    for (int i = 0; i < 4; ++i)
        #pragma unroll
        for (int j = 0; j < 4; ++j) acc[i][j] = (f32x4){0.f, 0.f, 0.f, 0.f};

    for (int k0 = 0; k0 < 1024; k0 += 64) {
        #pragma unroll
        for (int p = 0; p < 4; ++p) {
            int idx = p * 256 + tid;
            int row = idx >> 3, s = idx & 7;
            *(bf16x8*)&ash[row * 64 + ((s ^ (row & 7)) << 3)] =
                *(const bf16x8*)(w0b + (size_t)(o0 + row) * 2048 + l * 1024 + k0 + s * 8);
            *(bf16x8*)&bsh[row * 64 + ((s ^ (row & 7)) << 3)] =
                *(const bf16x8*)(tgt + (size_t)(c0 + row) * 1024 + k0 + s * 8);
        }
        __syncthreads();
        #pragma unroll
        for (int kk = 0; kk < 2; ++kk) {
            bf16x8 af[4], bfr[4];
            #pragma unroll
            for (int i = 0; i < 4; ++i) {
                int row = wm + i * 16 + (lane & 15);
                int s = kk * 4 + (lane >> 4);
                af[i] = *(const bf16x8*)&ash[row * 64 + ((s ^ (row & 7)) << 3)];
                int rowb = wn + i * 16 + (lane & 15);
                bfr[i] = *(const bf16x8*)&bsh[rowb * 64 + ((s ^ (rowb & 7)) << 3)];
            }
            #pragma unroll
            for (int i = 0; i < 4; ++i)
                #pragma unroll
                for (int j = 0; j < 4; ++j)
                    acc[i][j] = MFMA16(af[i], bfr[j], acc[i][j]);
        }
        __syncthreads();
    }
    u16* Eb = E + ((size_t)blockIdx.z * 1024 + o0) * 256 + c0;
    #pragma unroll
    for (int i = 0; i < 4; ++i)
        #pragma unroll
        for (int j = 0; j < 4; ++j)
            #pragma unroll
            for (int r = 0; r < 4; ++r) {
                int m = wm + i * 16 + ((lane >> 4) << 2) + r;
                int n = wn + j * 16 + (lane & 15);
                Eb[(size_t)m * 256 + n] = f2bf(acc[i][j][r]);
            }
}

// ---------------------------------------------------------------------------
// x0 GEMM: x0P[b][pad(s)][o] = BN+leaky( sum_{l,c} srcT_l[b][s][c]*E[(b,l)][o][c] )
// ---------------------------------------------------------------------------
__global__ __launch_bounds__(256) void x0_gemm(
    const u16* __restrict__ sA2,   // srcT or warpT layer2 [8][1024][256]
    const u16* __restrict__ sA3,
    const u16* __restrict__ E,     // [16][1024][256]
    const float* __restrict__ bng, const float* __restrict__ bnb,
    const float* __restrict__ bnm, const float* __restrict__ bnv,
    u16* __restrict__ x0P)         // [8][1156][1024] padded
{
    __shared__ u16 ash[128 * 64];
    __shared__ u16 bsh[128 * 64];
    const int o0 = blockIdx.x * 128;
    const int s0 = blockIdx.y * 128;
    const int b  = blockIdx.z;
    const int tid = threadIdx.x, lane = tid & 63, wid = tid >> 6;
    const int wm = (wid >> 1) * 64, wn = (wid & 1) * 64;

    f32x4 acc[4][4];
    #pragma unroll
    for (int i = 0; i < 4; ++i)
        #pragma unroll
        for (int j = 0; j < 4; ++j) acc[i][j] = (f32x4){0.f, 0.f, 0.f, 0.f};

    for (int kc = 0; kc < 8; ++kc) {
        const int l = kc >> 2;
        const int c0k = (kc & 3) * 64;
        const u16* sa = (l == 0 ? sA2 : sA3) + (size_t)b * 262144;
        const u16* eb = E + (size_t)((b << 1) + l) * 262144;
        #pragma unroll
        for (int p = 0; p < 4; ++p) {
            int idx = p * 256 + tid;
            int row = idx >> 3, s = idx & 7;
            *(bf16x8*)&ash[row * 64 + ((s ^ (row & 7)) << 3)] =
                *(const bf16x8*)(sa + (size_t)(s0 + row) * 256 + c0k + s * 8);
            *(bf16x8*)&bsh[row * 64 + ((s ^ (row & 7)) << 3)] =
                *(const bf16x8*)(eb + (size_t)(o0 + row) * 256 + c0k + s * 8);
        }
        __syncthreads();
        #pragma unroll
        for (int kk = 0; kk < 2; ++kk) {
            bf16x8 af[4], bfr[4];
            #pragma unroll
            for (int i = 0; i < 4; ++i) {
                int row = wm + i * 16 + (lane & 15);
                int s = kk * 4 + (lane >> 4);
                af[i] = *(const bf16x8*)&ash[row * 64 + ((s ^ (row & 7)) << 3)];
                int rowb = wn + i * 16 + (lane & 15);
                bfr[i] = *(const bf16x8*)&bsh[rowb * 64 + ((s ^ (rowb & 7)) << 3)];
            }
            #pragma unroll
            for (int i = 0; i < 4; ++i)
                #pragma unroll
                for (int j = 0; j < 4; ++j)
                    acc[i][j] = MFMA16(af[i], bfr[j], acc[i][j]);
        }
        __syncthreads();
    }
    #pragma unroll
    for (int j = 0; j < 4; ++j) {
        const int o = o0 + wn + j * 16 + (lane & 15);
        const float scv = bng[o] * rsqrtf(bnv[o] + BN_EPS);
        const float shv = bnb[o] - bnm[o] * scv;
        #pragma unroll
        for (int i = 0; i < 4; ++i)
            #pragma unroll
            for (int r = 0; r < 4; ++r) {
                int m = s0 + wm + i * 16 + ((lane >> 4) << 2) + r;
                float t = acc[i][j][r] * scv + shv;
                t = t >= 0.f ? t : SLOPE * t;
                size_t sp = (size_t)b * 1156 + ((m >> 5) + 1) * 34 + (m & 31) + 1;
                x0P[sp * 1024 + o] = f2bf(t);
            }
    }
}

// ---------------------------------------------------------------------------
// 3x3 conv as implicit GEMM over taps, PADDED input, register-prefetched.
// in: xP [8][1156][CIN], w: wpk [COUT][9][CIN]
// tile: MB cout x (NT*32) spatial; 4 waves (split in n), BK=32 cin
// per chunk: ds_write prefetched regs -> barrier -> issue next loads -> MFMA
// ---------------------------------------------------------------------------
template<int CIN, int COUT, int MB, int NT, bool PADOUT>
__global__ __launch_bounds__(256) void conv_gemm(
    const u16* __restrict__ xinP,
    const u16* __restrict__ wpk,
    const float* __restrict__ bng, const float* __restrict__ bnb,
    const float* __restrict__ bnm, const float* __restrict__ bnv,
    u16* __restrict__ xout)
{
    constexpr int NPOS = (NT + 2) * 34;
    constexpr int JT = NT / 2;       // n-frags per wave
    constexpr int WM = MB / 16;      // m-frags per wave
    constexpr int A_VEC = 9 * MB * 4;            // bf16x8 stores for A chunk
    constexpr int A_IT  = (A_VEC + 255) / 256;
    constexpr int B_VEC = NPOS * 4;
    constexpr int B_IT  = (B_VEC + 255) / 256;
    __shared__ u16 ash[9 * MB * 32];
    __shared__ u16 bsh[NPOS * 36];
    const int o0 = blockIdx.x * MB;
    const int y0 = blockIdx.y * NT;
    const int b  = blockIdx.z;
    const int tid = threadIdx.x, lane = tid & 63, wid = tid >> 6;
    const int wn = wid * (NT * 8);
    const u16* xpb = xinP + ((size_t)b * 1156 + y0 * 34) * CIN;

    f32x4 acc[WM][JT];
    #pragma unroll
    for (int i = 0; i < WM; ++i)
        #pragma unroll
        for (int j = 0; j < JT; ++j) acc[i][j] = (f32x4){0.f, 0.f, 0.f, 0.f};

    bf16x8 pa[A_IT], pb[B_IT];

    // prefetch chunk 0
    #pragma unroll
    for (int it = 0; it < A_IT; ++it) {
        int idx = it * 256 + tid;
        if (A_VEC % 256 == 0 || idx < A_VEC) {
            int p = idx / (MB * 4), row = (idx >> 2) % MB, s = idx & 3;
            pa[it] = *(const bf16x8*)(wpk + ((size_t)(o0 + row) * 9 + p) * CIN + s * 8);
        }
    }
    #pragma unroll
    for (int it = 0; it < B_IT; ++it) {
        int idx = it * 256 + tid;
        if (idx < B_VEC)
            pb[it] = *(const bf16x8*)(xpb + (size_t)(idx >> 2) * CIN + (idx & 3) * 8);
    }

    for (int c0 = 0; c0 < CIN; c0 += 32) {
        if (c0) __syncthreads();   // prev compute done reading LDS
        // LDS write from prefetched regs (compiler inserts vmcnt wait)
        #pragma unroll
        for (int it = 0; it < A_IT; ++it) {
            int idx = it * 256 + tid;
            if (A_VEC % 256 == 0 || idx < A_VEC) {
                int p = idx / (MB * 4), row = (idx >> 2) % MB, s = idx & 3;
                *(bf16x8*)&ash[((p * MB + row) << 5) + ((s ^ ((row >> 1) & 3)) << 3)] = pa[it];
            }
        }
        #pragma unroll
        for (int it = 0; it < B_IT; ++it) {
            int idx = it * 256 + tid;
            if (idx < B_VEC)
                *(bf16x8*)&bsh[(idx >> 2) * 36 + (idx & 3) * 8] = pb[it];
        }
        __syncthreads();
        // issue next chunk's global loads (in flight during MFMA below)
        if (c0 + 32 < CIN) {
            const int c1 = c0 + 32;
            #pragma unroll
            for (int it = 0; it < A_IT; ++it) {
                int idx = it * 256 + tid;
                if (A_VEC % 256 == 0 || idx < A_VEC) {
                    int p = idx / (MB * 4), row = (idx >> 2) % MB, s = idx & 3;
                    pa[it] = *(const bf16x8*)(wpk + ((size_t)(o0 + row) * 9 + p) * CIN + c1 + s * 8);
                }
            }
            #pragma unroll
            for (int it = 0; it < B_IT; ++it) {
                int idx = it * 256 + tid;
                if (idx < B_VEC)
                    pb[it] = *(const bf16x8*)(xpb + (size_t)(idx >> 2) * CIN + c1 + (idx & 3) * 8);
            }
        }
        #pragma unroll
        for (int t = 0; t < 9; ++t) {
            const int dy = t / 3, dx = t - dy * 3;
            bf16x8 af[WM], bfr[JT];
            #pragma unroll
            for (int i = 0; i < WM; ++i) {
                int row = i * 16 + (lane & 15);
                af[i] = *(const bf16x8*)&ash[((t * MB + row) << 5) +
                                             (((lane >> 4) ^ ((row >> 1) & 3)) << 3)];
            }
            #pragma unroll
            for (int j = 0; j < JT; ++j) {
                int n = wn + j * 16 + (lane & 15);
                int pos = ((n >> 5) + dy) * 34 + (n & 31) + dx;
                bfr[j] = *(const bf16x8*)&bsh[pos * 36 + ((lane >> 4) << 3)];
            }
            #pragma unroll
            for (int i = 0; i < WM; ++i)
                #pragma unroll
                for (int j = 0; j < JT; ++j)
                    acc[i][j] = MFMA16(af[i], bfr[j], acc[i][j]);
        }
    }
    #pragma unroll
    for (int i = 0; i < WM; ++i) {
        float scv[4], shv[4];
        #pragma unroll
        for (int r = 0; r < 4; ++r) {
            int o = o0 + i * 16 + ((lane >> 4) << 2) + r;
            float s = bng[o] * rsqrtf(bnv[o] + BN_EPS);
            scv[r] = s; shv[r] = bnb[o] - bnm[o] * s;
        }
        #pragma unroll
        for (int j = 0; j < JT; ++j) {
            int n = wn + j * 16 + (lane & 15);
            int yg = y0 + (n >> 5), xg = n & 31;
            size_t sp = PADOUT ? ((size_t)b * 1156 + (size_t)(yg + 1) * 34 + xg + 1)
                               : ((size_t)b * 1024 + (size_t)yg * 32 + xg);
            ushort4 pk;
            float t0 = acc[i][j][0] * scv[0] + shv[0]; t0 = t0 >= 0.f ? t0 : SLOPE * t0;
            float t1 = acc[i][j][1] * scv[1] + shv[1]; t1 = t1 >= 0.f ? t1 : SLOPE * t1;
            float t2 = acc[i][j][2] * scv[2] + shv[2]; t2 = t2 >= 0.f ? t2 : SLOPE * t2;
            float t3 = acc[i][j][3] * scv[3] + shv[3]; t3 = t3 >= 0.f ? t3 : SLOPE * t3;
            pk.x = f2bf(t0); pk.y = f2bf(t1); pk.z = f2bf(t2); pk.w = f2bf(t3);
            *(ushort4*)&xout[sp * COUT + o0 + i * 16 + ((lane >> 4) << 2)] = pk;
        }
    }
}

// ---------------------------------------------------------------------------
// grid_sample on transposed layout
// ---------------------------------------------------------------------------
__global__ __launch_bounds__(64) void warp_kernel(
    const u16* __restrict__ srcT,   // [8][1024][256]
    const float* __restrict__ flow, // [8][1024][2]
    u16* __restrict__ outT)         // [8][1024][256]
{
    const int bs = blockIdx.x;
    const int b = bs >> 10;
    const float fx = flow[(size_t)bs * 2 + 0];
    const float fy = flow[(size_t)bs * 2 + 1];
    const float px = (fx + 1.f) * 15.5f;
    const float py = (fy + 1.f) * 15.5f;
    const float x0f = floorf(px), y0f = floorf(py);
    const int x0 = (int)x0f, y0 = (int)y0f;
    const float wx1 = px - x0f, wx0 = 1.f - wx1;
    const float wy1 = py - y0f, wy0 = 1.f - wy1;
    const int lane = threadIdx.x;
    const u16* sb = srcT + (size_t)b * 262144 + lane * 4;
    float a0 = 0.f, a1 = 0.f, a2 = 0.f, a3 = 0.f;
    #pragma unroll
    for (int cr = 0; cr < 4; ++cr) {
        const int xi = x0 + (cr & 1), yi = y0 + (cr >> 1);
        const float w = (cr == 0 ? wx0 * wy0 : cr == 1 ? wx1 * wy0 :
                         cr == 2 ? wx0 * wy1 : wx1 * wy1);
        if (xi >= 0 && xi < 32 && yi >= 0 && yi < 32) {
            const ushort4 v = *(const ushort4*)(sb + (size_t)(yi * 32 + xi) * 256);
            a0 += w * bf2f(v.x); a1 += w * bf2f(v.y);
            a2 += w * bf2f(v.z); a3 += w * bf2f(v.w);
        }
    }
    ushort4 o;
    o.x = f2bf(a0); o.y = f2bf(a1); o.z = f2bf(a2); o.w = f2bf(a3);
    *(ushort4*)(outT + (size_t)bs * 256 + lane * 4) = o;
}

// ---------------------------------------------------------------------------
// conv3 (1x1, 256->2) + bias + flow update; one wave per (b,s)
// ---------------------------------------------------------------------------
__global__ __launch_bounds__(256) void conv3_flow(
    const u16* __restrict__ x2T,   // [8][1024][256]
    const float* __restrict__ w3s, // [2][256]
    const float* __restrict__ b3s, // [2]
    float* __restrict__ flow, int add_ident)
{
    const int widx = blockIdx.x * 4 + (threadIdx.x >> 6);
    const int lane = threadIdx.x & 63;
    const ushort4 v = *(const ushort4*)&x2T[(size_t)widx * 256 + lane * 4];
    float a0 = 0.f, a1 = 0.f;
    const u16* vp = (const u16*)&v;
    #pragma unroll
    for (int j = 0; j < 4; ++j) {
        const float xv = bf2f(vp[j]);
        a0 += xv * w3s[lane * 4 + j];
        a1 += xv * w3s[256 + lane * 4 + j];
    }
    #pragma unroll
    for (int off = 32; off > 0; off >>= 1) {
        a0 += __shfl_down(a0, off);
        a1 += __shfl_down(a1, off);
    }
    if (lane == 0) {
        a0 += b3s[0]; a1 += b3s[1];
        float* f = flow + (size_t)widx * 2;
        if (add_ident) {
            const int s = widx & 1023;
            const int yy = s >> 5, xx = s & 31;
            f[0] = a0 + (-1.f + xx * (2.f / 31.f));
            f[1] = a1 + (-1.f + yy * (2.f / 31.f));
        } else {
            f[0] += a0;
            f[1] += a1;
        }
    }
}

__global__ __launch_bounds__(256) void copy_flow_kernel(
    const float* __restrict__ flow, float* __restrict__ out, int n)
{
    const int i = blockIdx.x * 256 + threadIdx.x;
    if (i < n) out[i] = flow[i];
}

// ---------------------------------------------------------------------------
extern "C" void kernel_launch(void* const* d_in, const int* in_sizes, int n_in,
                              void* d_out, int out_size, void* d_ws, size_t ws_size,
                              hipStream_t stream) {
    (void)in_sizes; (void)n_in; (void)ws_size;
    const float* src2 = (const float*)d_in[0];
    const float* src3 = (const float*)d_in[1];
    const float* tgt2 = (const float*)d_in[2];
    const float* tgt3 = (const float*)d_in[3];
    const float* w0   = (const float*)d_in[4];
    const float* w1   = (const float*)d_in[5];
    const float* w2   = (const float*)d_in[6];
    const float* w3   = (const float*)d_in[7];
    const float* b3   = (const float*)d_in[8];
    const float* bn0g = (const float*)d_in[9];
    const float* bn0b = (const float*)d_in[10];
    const float* bn0m = (const float*)d_in[11];
    const float* bn0v = (const float*)d_in[12];
    const float* bn1g = (const float*)d_in[13];
    const float* bn1b = (const float*)d_in[14];
    const float* bn1m = (const float*)d_in[15];
    const float* bn1v = (const float*)d_in[16];
    const float* bn2g = (const float*)d_in[17];
    const float* bn2b = (const float*)d_in[18];
    const float* bn2m = (const float*)d_in[19];
    const float* bn2v = (const float*)d_in[20];

    u16* ws = (u16*)d_ws;
    u16* tgt2b  = ws + OFF_TGT2B;
    u16* tgt3b  = ws + OFF_TGT3B;
    u16* srcT2  = ws + OFF_SRCT2;
    u16* srcT3  = ws + OFF_SRCT3;
    u16* warpT2 = ws + OFF_WARPT2;
    u16* warpT3 = ws + OFF_WARPT3;
    u16* wpk1   = ws + OFF_WPK1;
    u16* wpk2   = ws + OFF_WPK2;
    u16* E      = ws + OFF_EX1;
    u16* x1P    = ws + OFF_EX1;     // alias: E dead after x0_gemm
    u16* x0P    = ws + OFF_X0P;
    u16* w0b    = ws + OFF_X0P;     // alias: w0b dead after e_gemm
    u16* x2T    = ws + OFF_WARPT2;  // alias: warpT2 dead after x0_gemm
    float* flow = (float*)(ws + OFF_FLOW);

    // one-time conversions
    cvt_kernel<<<2048, 256, 0, stream>>>(tgt2, tgt2b, 2097152);
    cvt_kernel<<<2048, 256, 0, stream>>>(tgt3, tgt3b, 2097152);
    transpose_cvt<<<dim3(32, 8, 8), 256, 0, stream>>>(src2, srcT2);
    transpose_cvt<<<dim3(32, 8, 8), 256, 0, stream>>>(src3, srcT3);

    for (int sc = 0; sc < 3; ++sc) {
        cvt_kernel<<<2048, 256, 0, stream>>>(w0 + (size_t)sc * 2097152, w0b, 2097152);
        pack_conv_w<<<2048, 256, 0, stream>>>(w1 + (size_t)sc * 4718592, wpk1, 512, 1024);
        pack_conv_w<<<512, 256, 0, stream>>>(w2 + (size_t)sc * 1179648, wpk2, 256, 512);

        const u16* a2 = srcT2;
        const u16* a3 = srcT3;
        if (sc > 0) {
            warp_kernel<<<8192, 64, 0, stream>>>(srcT2, flow, warpT2);
            warp_kernel<<<8192, 64, 0, stream>>>(srcT3, flow, warpT3);
            a2 = warpT2; a3 = warpT3;
        }
        e_gemm<<<dim3(2, 8, 16), 256, 0, stream>>>(w0b, tgt2b, tgt3b, E);
        // x0P pads: safe here (x0P aliases only w0b, dead after e_gemm)
        zero_pads<1024><<<528, 256, 0, stream>>>(x0P);
        x0_gemm<<<dim3(8, 8, 8), 256, 0, stream>>>(a2, a3, E,
            bn0g + sc * 1024, bn0b + sc * 1024, bn0m + sc * 1024, bn0v + sc * 1024, x0P);
        // x1P pads: MUST be after x0_gemm (x1P aliases E)
        zero_pads<512><<<264, 256, 0, stream>>>(x1P);
        conv_gemm<1024, 512, 64, 4, true><<<dim3(8, 8, 8), 256, 0, stream>>>(x0P, wpk1,
            bn1g + sc * 512, bn1b + sc * 512, bn1m + sc * 512, bn1v + sc * 512, x1P);
        conv_gemm<512, 256, 32, 4, false><<<dim3(8, 8, 8), 256, 0, stream>>>(x1P, wpk2,
            bn2g + sc * 256, bn2b + sc * 256, bn2m + sc * 256, bn2v + sc * 256, x2T);
        conv3_flow<<<2048, 256, 0, stream>>>(x2T, w3 + sc * 512, b3 + sc * 2,
                                             flow, sc == 0 ? 1 : 0);
    }
    copy_flow_kernel<<<64, 256, 0, stream>>>(flow, (float*)d_out, out_size);
}